// Round 2
// baseline (284.201 us; speedup 1.0000x reference)
//
#include <hip/hip_runtime.h>
#include <stdint.h>

typedef unsigned int   u32;
typedef unsigned short u16;
typedef __bf16 bf16x8 __attribute__((ext_vector_type(8)));
typedef float  f32x4  __attribute__((ext_vector_type(4)));

// ---------------------------------------------------------------------------
// Compile-time DWT analysis matrix Wd[84][64]:
//   coeffs = Wd @ x  for a length-64 signal, db4, mode='reflect', J=3.
// Row order: lo3 (14) | hi1 (35) | hi2 (21) | hi3 (14).
// ---------------------------------------------------------------------------
struct WdT { float v[84][64]; };

constexpr WdT build_wd() {
    WdT W{};
    const float GLc[8] = { 0.23037781330885523f,  0.7148465705525415f,
                           0.6308807679295904f,  -0.02798376941698385f,
                          -0.18703481171888114f,  0.030841381835986965f,
                           0.032883011666982945f,-0.010597401784997278f };
    const float GHc[8] = {-0.010597401784997278f,-0.032883011666982945f,
                           0.030841381835986965f, 0.18703481171888114f,
                          -0.02798376941698385f, -0.6308807679295904f,
                           0.7148465705525415f,  -0.23037781330885523f };
    for (int j = 0; j < 64; ++j) {
        float lo1[35] = {}, lo2[21] = {};
        for (int i = 0; i < 35; ++i) {            // level 1: N=64, reflect 6
            float sl = 0.f, sh = 0.f;
            for (int t = 0; t < 8; ++t) {
                int s = 2*i + t - 6;
                if (s < 0)   s = -s;
                if (s >= 64) s = 126 - s;
                if (s == j) { sl += GLc[t]; sh += GHc[t]; }
            }
            lo1[i] = sl; W.v[14 + i][j] = sh;
        }
        for (int i = 0; i < 21; ++i) {            // level 2: N=35 (+1 zero)
            float sl = 0.f, sh = 0.f;
            for (int t = 0; t < 8; ++t) {
                int s = 2*i + t - 6;
                if (s < 0)   s = -s;
                if (s >= 36) s = 70 - s;
                if (s < 35) { sl += lo1[s]*GLc[t]; sh += lo1[s]*GHc[t]; }
            }
            lo2[i] = sl; W.v[49 + i][j] = sh;
        }
        for (int i = 0; i < 14; ++i) {            // level 3: N=21 (+1 zero)
            float sl = 0.f, sh = 0.f;
            for (int t = 0; t < 8; ++t) {
                int s = 2*i + t - 6;
                if (s < 0)   s = -s;
                if (s >= 22) s = 42 - s;
                if (s < 21) { sl += lo2[s]*GLc[t]; sh += lo2[s]*GHc[t]; }
            }
            W.v[i][j] = sl; W.v[70 + i][j] = sh;
        }
    }
    return W;
}

__constant__ WdT WD = build_wd();

__device__ inline u16 f32_bf16(float f) {
    u32 u = __float_as_uint(f);
    u += 0x7fffu + ((u >> 16) & 1u);
    return (u16)(u >> 16);
}
__device__ inline u32 pack2_bf16(float a, float b) {
    u32 ua = __float_as_uint(a); ua += 0x7fffu + ((ua >> 16) & 1u);
    u32 ub = __float_as_uint(b); ub += 0x7fffu + ((ub >> 16) & 1u);
    return (ua >> 16) | (ub & 0xffff0000u);
}

// ---------------------------------------------------------------------------
// Kernel 1: fold conv weights with the constant DWT matrix, emitting bf16
// in MFMA B-fragment order, kb-contiguous:
//   Wf[(((s*128 + kb)*8 + nt)*64 + lane)*8 + j]
//     = Wp[n = nt*16 + (lane&15)][K = kb*32 + (lane>>4)*8 + j]
// where Wp[n][K = sigma*64 + hw] = sum_tau cw[s,n,tau,hw] * Wd[tau][sigma].
// One block per (s,n).  WD[tau][t0+j] is wave-uniform -> scalar K$ loads.
// ---------------------------------------------------------------------------
__global__ __launch_bounds__(256) void fold_w(const float* __restrict__ cw,
                                              u16* __restrict__ Wf) {
    const int tid = threadIdx.x;
    const int sk  = blockIdx.x;                  // 0..511 = s*128 + n
    const int s   = sk >> 7;
    const int n   = sk & 127;
    const int hw  = tid & 63;
    const int tg  = __builtin_amdgcn_readfirstlane((int)(tid >> 6)); // 0..3
    const int t0  = tg * 16;
    const float* wk = cw + (size_t)sk * (84 * 64);

    float acc[16];
#pragma unroll
    for (int j = 0; j < 16; ++j) acc[j] = 0.f;

#pragma unroll 4
    for (int tau = 0; tau < 84; ++tau) {
        const float wv = wk[tau * 64 + hw];      // coalesced 256 B / wave
#pragma unroll
        for (int j = 0; j < 16; ++j) acc[j] += wv * WD.v[tau][t0 + j]; // s_load
    }

    // scatter into kb-contiguous B-fragment layout
    const int nt  = n >> 4;
    const int fr  = n & 15;
    const int fq  = (hw >> 3) & 3;
    const int jj  = hw & 7;
    const int kbh = hw >> 5;                     // kb = sigma*2 + (hw>>5)
#pragma unroll
    for (int j = 0; j < 16; ++j) {
        const int t = t0 + j;                    // sigma
        const size_t idx =
            ((((size_t)(s * 128 + t * 2 + kbh)) * 8 + nt) * 64 + fq * 16 + fr) * 8 + jj;
        Wf[idx] = f32_bf16(acc[j]);
    }
}

// ---------------------------------------------------------------------------
// Kernel 2: fused MFMA GEMM + K-reduction + bias + leaky-ReLU.
// Grid 512 blocks (XCD-swizzled) = (s 0..3) x (mt 0..127); 8 waves/block.
// Wave w computes the 16(m) x 128(n) tile over K-slice [w*512,(w+1)*512)
// with register double-buffered B (distance 1 kb) and A prefetch distance
// 2 kb, then all waves reduce via LDS atomics; epilogue applies
// bias + leakyReLU and writes the final 16x128 tile.
// ---------------------------------------------------------------------------
__global__ __launch_bounds__(512, 4) void gemm_f(const float* __restrict__ X,
                                                 const u16* __restrict__ Wf,
                                                 const float* __restrict__ bias,
                                                 float* __restrict__ out) {
    __shared__ __align__(16) float R[16 * 132];  // +4 pad: 2-way banks = free
    const int tid  = threadIdx.x;
    const int lane = tid & 63;
    const int w    = tid >> 6;                   // K-slice 0..7
    const int bid  = blockIdx.x;                 // 512 % 8 == 0 -> bijective
    const int wgid = ((bid & 7) << 6) + (bid >> 3);  // XCD-chunked swizzle
    const int s    = wgid >> 7;                  // subwindow
    const int mt   = wgid & 127;                 // m-tile (16 rows)
    const int fr   = lane & 15;
    const int fq   = lane >> 4;
    const int kb0  = w * 16;

    for (int i = tid; i < 16 * 132; i += 512) R[i] = 0.f;
    __syncthreads();                             // before prefetch: vmcnt drain is free

    const float* xg = X + (size_t)(mt * 16 + fr) * 16384 + s * 4096 + kb0 * 32 + fq * 8;
    const f32x4* xa = reinterpret_cast<const f32x4*>(xg);     // kb stride = 8
    const u16*   wg = Wf + (size_t)(s * 128 + kb0) * 8 * 512 + lane * 8;
    // strides (u16): kb -> 8*512 = 4096 ; nt -> 512 (8 KB contiguous per kb)

    f32x4 acc[8];
#pragma unroll
    for (int nt = 0; nt < 8; ++nt) acc[nt] = (f32x4){0.f, 0.f, 0.f, 0.f};

    f32x4  abuf[2][2];                           // A prefetch, distance 2 kb
    bf16x8 bbuf[2][8];                           // B double buffer, distance 1 kb

    abuf[0][0] = __builtin_nontemporal_load(xa + 0);
    abuf[0][1] = __builtin_nontemporal_load(xa + 1);
    abuf[1][0] = __builtin_nontemporal_load(xa + 8);
    abuf[1][1] = __builtin_nontemporal_load(xa + 9);
#pragma unroll
    for (int nt = 0; nt < 8; ++nt)
        bbuf[0][nt] = *reinterpret_cast<const bf16x8*>(wg + nt * 512);

#pragma unroll
    for (int kb = 0; kb < 16; ++kb) {            // full unroll: all idx static
        const int cur = kb & 1, nxt = cur ^ 1;
        if (kb + 1 < 16) {                       // issue next B (L2, ~1 phase cover)
            const u16* wb = wg + (size_t)(kb + 1) * 4096;
#pragma unroll
            for (int nt = 0; nt < 8; ++nt)
                bbuf[nxt][nt] = *reinterpret_cast<const bf16x8*>(wb + nt * 512);
        }
        union { u32 u[4]; bf16x8 v; } av;
        av.u[0] = pack2_bf16(abuf[cur][0].x, abuf[cur][0].y);
        av.u[1] = pack2_bf16(abuf[cur][0].z, abuf[cur][0].w);
        av.u[2] = pack2_bf16(abuf[cur][1].x, abuf[cur][1].y);
        av.u[3] = pack2_bf16(abuf[cur][1].z, abuf[cur][1].w);
        if (kb + 2 < 16) {                       // issue A (HBM, ~2 phase cover)
            abuf[cur][0] = __builtin_nontemporal_load(xa + (kb + 2) * 8);
            abuf[cur][1] = __builtin_nontemporal_load(xa + (kb + 2) * 8 + 1);
        }
#pragma unroll
        for (int nt = 0; nt < 8; ++nt)
            acc[nt] = __builtin_amdgcn_mfma_f32_16x16x32_bf16(av.v, bbuf[cur][nt],
                                                              acc[nt], 0, 0, 0);
    }

    // in-block K reduction: acc[nt][r] -> row fq*4+r, col nt*16+fr
#pragma unroll
    for (int nt = 0; nt < 8; ++nt)
#pragma unroll
        for (int r = 0; r < 4; ++r)
            atomicAdd(&R[(fq * 4 + r) * 132 + nt * 16 + fr], acc[nt][r]);
    __syncthreads();

    // epilogue: 512 threads x 4 outputs = 16x128 tile
    {
        const int o   = tid * 4;                 // 0..2044
        const int row = o >> 7;
        const int col = o & 127;
        f32x4 v = *reinterpret_cast<const f32x4*>(&R[row * 132 + col]);
        const f32x4 b = *reinterpret_cast<const f32x4*>(bias + s * 128 + col);
        f32x4 u = v + b;
        u.x = u.x > 0.f ? u.x : 0.01f * u.x;
        u.y = u.y > 0.f ? u.y : 0.01f * u.y;
        u.z = u.z > 0.f ? u.z : 0.01f * u.z;
        u.w = u.w > 0.f ? u.w : 0.01f * u.w;
        __builtin_nontemporal_store(
            u, reinterpret_cast<f32x4*>(out + (size_t)(mt * 16 + row) * 512 + s * 128 + col));
    }
}

// ---------------------------------------------------------------------------
extern "C" void kernel_launch(void* const* d_in, const int* in_sizes, int n_in,
                              void* d_out, int out_size, void* d_ws, size_t ws_size,
                              hipStream_t stream) {
    const float* x  = (const float*)d_in[0];   // [2048,1,256,8,8] fp32
    const float* cw = (const float*)d_in[1];   // [4,128,84,8,8]   fp32
    const float* cb = (const float*)d_in[2];   // [4,128]          fp32
    float* out = (float*)d_out;                // [2048,512]       fp32

    u16* Wf = (u16*)d_ws;                      // 4 MiB, B-fragment order

    fold_w<<<512, 256, 0, stream>>>(cw, Wf);
    gemm_f<<<512, 512, 0, stream>>>(x, Wf, cb, out);
}

// Round 3
// 257.991 us; speedup vs baseline: 1.1016x; 1.1016x over previous
//
#include <hip/hip_runtime.h>
#include <stdint.h>

typedef unsigned int   u32;
typedef unsigned short u16;
typedef __bf16 bf16x8 __attribute__((ext_vector_type(8)));
typedef float  f32x4  __attribute__((ext_vector_type(4)));
typedef float  f32x2  __attribute__((ext_vector_type(2)));

// ---------------------------------------------------------------------------
// Compile-time DWT analysis matrix Wd[84][64]:
//   coeffs = Wd @ x  for a length-64 signal, db4, mode='reflect', J=3.
// Row order: lo3 (14) | hi1 (35) | hi2 (21) | hi3 (14).
// ---------------------------------------------------------------------------
struct WdT { float v[84][64]; };

constexpr WdT build_wd() {
    WdT W{};
    const float GLc[8] = { 0.23037781330885523f,  0.7148465705525415f,
                           0.6308807679295904f,  -0.02798376941698385f,
                          -0.18703481171888114f,  0.030841381835986965f,
                           0.032883011666982945f,-0.010597401784997278f };
    const float GHc[8] = {-0.010597401784997278f,-0.032883011666982945f,
                           0.030841381835986965f, 0.18703481171888114f,
                          -0.02798376941698385f, -0.6308807679295904f,
                           0.7148465705525415f,  -0.23037781330885523f };
    for (int j = 0; j < 64; ++j) {
        float lo1[35] = {}, lo2[21] = {};
        for (int i = 0; i < 35; ++i) {            // level 1: N=64, reflect 6
            float sl = 0.f, sh = 0.f;
            for (int t = 0; t < 8; ++t) {
                int s = 2*i + t - 6;
                if (s < 0)   s = -s;
                if (s >= 64) s = 126 - s;
                if (s == j) { sl += GLc[t]; sh += GHc[t]; }
            }
            lo1[i] = sl; W.v[14 + i][j] = sh;
        }
        for (int i = 0; i < 21; ++i) {            // level 2: N=35 (+1 zero)
            float sl = 0.f, sh = 0.f;
            for (int t = 0; t < 8; ++t) {
                int s = 2*i + t - 6;
                if (s < 0)   s = -s;
                if (s >= 36) s = 70 - s;
                if (s < 35) { sl += lo1[s]*GLc[t]; sh += lo1[s]*GHc[t]; }
            }
            lo2[i] = sl; W.v[49 + i][j] = sh;
        }
        for (int i = 0; i < 14; ++i) {            // level 3: N=21 (+1 zero)
            float sl = 0.f, sh = 0.f;
            for (int t = 0; t < 8; ++t) {
                int s = 2*i + t - 6;
                if (s < 0)   s = -s;
                if (s >= 22) s = 42 - s;
                if (s < 21) { sl += lo2[s]*GLc[t]; sh += lo2[s]*GHc[t]; }
            }
            W.v[i][j] = sl; W.v[70 + i][j] = sh;
        }
    }
    return W;
}

__constant__ WdT WD = build_wd();

__device__ inline u16 f32_bf16(float f) {
    u32 u = __float_as_uint(f);
    u += 0x7fffu + ((u >> 16) & 1u);
    return (u16)(u >> 16);
}
__device__ inline u32 pack2_bf16(float a, float b) {
    u32 ua = __float_as_uint(a); ua += 0x7fffu + ((ua >> 16) & 1u);
    u32 ub = __float_as_uint(b); ub += 0x7fffu + ((ub >> 16) & 1u);
    return (ua >> 16) | (ub & 0xffff0000u);
}

// ---------------------------------------------------------------------------
// Kernel 1: fold conv weights with the constant DWT matrix, emitting bf16
// in MFMA B-fragment order, kb-contiguous:
//   Wf[(((s*128 + kb)*8 + nt)*64 + lane)*8 + j]
//     = Wp[n = nt*16 + (lane&15)][K = kb*32 + (lane>>4)*8 + j]
// where Wp[n][K = sigma*64 + hw] = sum_tau cw[s,n,tau,hw] * Wd[tau][sigma].
// One block per (s,n).  WD[tau][t0+j] is wave-uniform -> scalar K$ loads.
// ---------------------------------------------------------------------------
__global__ __launch_bounds__(256) void fold_w(const float* __restrict__ cw,
                                              u16* __restrict__ Wf) {
    const int tid = threadIdx.x;
    const int sk  = blockIdx.x;                  // 0..511 = s*128 + n
    const int s   = sk >> 7;
    const int n   = sk & 127;
    const int hw  = tid & 63;
    const int tg  = __builtin_amdgcn_readfirstlane((int)(tid >> 6)); // 0..3
    const int t0  = tg * 16;
    const float* wk = cw + (size_t)sk * (84 * 64);

    float acc[16];
#pragma unroll
    for (int j = 0; j < 16; ++j) acc[j] = 0.f;

#pragma unroll 4
    for (int tau = 0; tau < 84; ++tau) {
        const float wv = wk[tau * 64 + hw];      // coalesced 256 B / wave
#pragma unroll
        for (int j = 0; j < 16; ++j) acc[j] += wv * WD.v[tau][t0 + j]; // s_load
    }

    // scatter into kb-contiguous B-fragment layout
    const int nt  = n >> 4;
    const int fr  = n & 15;
    const int fq  = (hw >> 3) & 3;
    const int jj  = hw & 7;
    const int kbh = hw >> 5;                     // kb = sigma*2 + (hw>>5)
#pragma unroll
    for (int j = 0; j < 16; ++j) {
        const int t = t0 + j;                    // sigma
        const size_t idx =
            ((((size_t)(s * 128 + t * 2 + kbh)) * 8 + nt) * 64 + fq * 16 + fr) * 8 + jj;
        Wf[idx] = f32_bf16(acc[j]);
    }
}

// ---------------------------------------------------------------------------
// Kernel 2: fused MFMA GEMM + K-reduction + bias + leaky-ReLU.
// Grid 1024 blocks (XCD-swizzled) = (s 0..3) x (mt 0..127) x (nh 0..1);
// 8 waves/block, wave w covers K-slice [w*512,(w+1)*512) x 64 n-cols.
// 8192 waves total = 100% grid occupancy; __launch_bounds__(512,8) caps
// VGPR at 64 -> 4 blocks/CU.  X loads are plain (L3-resident across iters).
// LDS-atomic K-reduction, then bias + leakyReLU epilogue.
// ---------------------------------------------------------------------------
__global__ __launch_bounds__(512, 8) void gemm_f(const float* __restrict__ X,
                                                 const u16* __restrict__ Wf,
                                                 const float* __restrict__ bias,
                                                 float* __restrict__ out) {
    __shared__ __align__(16) float R[16 * 68];   // 16 rows x 64 cols (+4 pad)
    const int tid  = threadIdx.x;
    const int lane = tid & 63;
    const int w    = tid >> 6;                   // K-slice 0..7
    const int bid  = blockIdx.x;                 // 1024 % 8 == 0 -> bijective
    const int wgid = ((bid & 7) << 7) + (bid >> 3);  // XCD-chunked swizzle
    const int nh   = wgid & 1;                   // n-half (64 cols)
    const int mt   = (wgid >> 1) & 127;          // m-tile (16 rows)
    const int s    = wgid >> 8;                  // subwindow
    const int fr   = lane & 15;
    const int fq   = lane >> 4;
    const int kb0  = w * 16;

    for (int i = tid; i < 16 * 68; i += 512) R[i] = 0.f;
    __syncthreads();

    const float* xg = X + (size_t)(mt * 16 + fr) * 16384 + s * 4096 + kb0 * 32 + fq * 8;
    const f32x4* xa = reinterpret_cast<const f32x4*>(xg);     // kb stride = 8 vecs
    const u16*   wg = Wf + ((size_t)(s * 128 + kb0) * 8 + nh * 4) * 512 + lane * 8;
    // strides (u16): kb -> 8*512 = 4096 ; nt -> 512

    f32x4 acc[4];
#pragma unroll
    for (int nt = 0; nt < 4; ++nt) acc[nt] = (f32x4){0.f, 0.f, 0.f, 0.f};

#pragma unroll
    for (int kb = 0; kb < 16; ++kb) {
        const f32x4 a0 = xa[kb * 8];
        const f32x4 a1 = xa[kb * 8 + 1];
        union { u32 u[4]; bf16x8 v; } av;
        av.u[0] = pack2_bf16(a0.x, a0.y); av.u[1] = pack2_bf16(a0.z, a0.w);
        av.u[2] = pack2_bf16(a1.x, a1.y); av.u[3] = pack2_bf16(a1.z, a1.w);
        const u16* wb = wg + (size_t)kb * 4096;
#pragma unroll
        for (int nt = 0; nt < 4; ++nt) {
            const bf16x8 bf = *reinterpret_cast<const bf16x8*>(wb + nt * 512);
            acc[nt] = __builtin_amdgcn_mfma_f32_16x16x32_bf16(av.v, bf, acc[nt], 0, 0, 0);
        }
    }

    // in-block K reduction: acc[nt][r] -> row fq*4+r, col nt*16+fr
#pragma unroll
    for (int nt = 0; nt < 4; ++nt)
#pragma unroll
        for (int r = 0; r < 4; ++r)
            atomicAdd(&R[(fq * 4 + r) * 68 + nt * 16 + fr], acc[nt][r]);
    __syncthreads();

    // epilogue: 512 threads x 2 outputs = 16x64 tile
    {
        const int o     = tid * 2;               // 0..1022
        const int row   = o >> 6;
        const int col64 = o & 63;
        const f32x2 v = *reinterpret_cast<const f32x2*>(&R[row * 68 + col64]);
        const f32x2 b = *reinterpret_cast<const f32x2*>(bias + s * 128 + nh * 64 + col64);
        f32x2 u = v + b;
        u.x = u.x > 0.f ? u.x : 0.01f * u.x;
        u.y = u.y > 0.f ? u.y : 0.01f * u.y;
        *reinterpret_cast<f32x2*>(
            out + (size_t)(mt * 16 + row) * 512 + s * 128 + nh * 64 + col64) = u;
    }
}

// ---------------------------------------------------------------------------
extern "C" void kernel_launch(void* const* d_in, const int* in_sizes, int n_in,
                              void* d_out, int out_size, void* d_ws, size_t ws_size,
                              hipStream_t stream) {
    const float* x  = (const float*)d_in[0];   // [2048,1,256,8,8] fp32
    const float* cw = (const float*)d_in[1];   // [4,128,84,8,8]   fp32
    const float* cb = (const float*)d_in[2];   // [4,128]          fp32
    float* out = (float*)d_out;                // [2048,512]       fp32

    u16* Wf = (u16*)d_ws;                      // 4 MiB, B-fragment order

    fold_w<<<512, 256, 0, stream>>>(cw, Wf);
    gemm_f<<<1024, 512, 0, stream>>>(x, Wf, cb, out);
}

// Round 4
// 233.805 us; speedup vs baseline: 1.2155x; 1.1034x over previous
//
#include <hip/hip_runtime.h>
#include <stdint.h>

typedef unsigned int   u32;
typedef unsigned short u16;
typedef __bf16 bf16x8 __attribute__((ext_vector_type(8)));
typedef float  f32x4  __attribute__((ext_vector_type(4)));

// ---------------------------------------------------------------------------
// Compile-time DWT analysis matrix Wd[84][64] (db4, reflect, J=3).
// Row order: lo3 (14) | hi1 (35) | hi2 (21) | hi3 (14).
// ---------------------------------------------------------------------------
struct WdT { float v[84][64]; };

constexpr WdT build_wd() {
    WdT W{};
    const float GLc[8] = { 0.23037781330885523f,  0.7148465705525415f,
                           0.6308807679295904f,  -0.02798376941698385f,
                          -0.18703481171888114f,  0.030841381835986965f,
                           0.032883011666982945f,-0.010597401784997278f };
    const float GHc[8] = {-0.010597401784997278f,-0.032883011666982945f,
                           0.030841381835986965f, 0.18703481171888114f,
                          -0.02798376941698385f, -0.6308807679295904f,
                           0.7148465705525415f,  -0.23037781330885523f };
    for (int j = 0; j < 64; ++j) {
        float lo1[35] = {}, lo2[21] = {};
        for (int i = 0; i < 35; ++i) {
            float sl = 0.f, sh = 0.f;
            for (int t = 0; t < 8; ++t) {
                int s = 2*i + t - 6;
                if (s < 0)   s = -s;
                if (s >= 64) s = 126 - s;
                if (s == j) { sl += GLc[t]; sh += GHc[t]; }
            }
            lo1[i] = sl; W.v[14 + i][j] = sh;
        }
        for (int i = 0; i < 21; ++i) {
            float sl = 0.f, sh = 0.f;
            for (int t = 0; t < 8; ++t) {
                int s = 2*i + t - 6;
                if (s < 0)   s = -s;
                if (s >= 36) s = 70 - s;
                if (s < 35) { sl += lo1[s]*GLc[t]; sh += lo1[s]*GHc[t]; }
            }
            lo2[i] = sl; W.v[49 + i][j] = sh;
        }
        for (int i = 0; i < 14; ++i) {
            float sl = 0.f, sh = 0.f;
            for (int t = 0; t < 8; ++t) {
                int s = 2*i + t - 6;
                if (s < 0)   s = -s;
                if (s >= 22) s = 42 - s;
                if (s < 21) { sl += lo2[s]*GLc[t]; sh += lo2[s]*GHc[t]; }
            }
            W.v[i][j] = sl; W.v[70 + i][j] = sh;
        }
    }
    return W;
}

__constant__ WdT WD = build_wd();

__device__ inline u16 f32_bf16(float f) {
    u32 u = __float_as_uint(f);
    u += 0x7fffu + ((u >> 16) & 1u);
    return (u16)(u >> 16);
}
__device__ inline u32 pack2_bf16(float a, float b) {
    u32 ua = __float_as_uint(a); ua += 0x7fffu + ((ua >> 16) & 1u);
    u32 ub = __float_as_uint(b); ub += 0x7fffu + ((ub >> 16) & 1u);
    return (ua >> 16) | (ub & 0xffff0000u);
}

// async 16-byte global -> LDS (fire-and-forget; counted by vmcnt)
typedef const __attribute__((address_space(1))) u32 gas_u32;
typedef __attribute__((address_space(3)))       u32 las_u32;
__device__ inline void gl16(const void* g, void* l) {
    __builtin_amdgcn_global_load_lds((gas_u32*)g, (las_u32*)l, 16, 0, 0);
}

// ---------------------------------------------------------------------------
// Kernel 1: fold conv weights with the constant DWT matrix, emitting bf16
// in MFMA B-fragment order, kb-contiguous:
//   Wf[(((s*128 + kb)*8 + nt)*64 + lane)*8 + j]
//     = Wp[n = nt*16 + (lane&15)][K = kb*32 + (lane>>4)*8 + j]
// ---------------------------------------------------------------------------
__global__ __launch_bounds__(256) void fold_w(const float* __restrict__ cw,
                                              u16* __restrict__ Wf) {
    const int tid = threadIdx.x;
    const int sk  = blockIdx.x;                  // 0..511 = s*128 + n
    const int s   = sk >> 7;
    const int n   = sk & 127;
    const int hw  = tid & 63;
    const int tg  = __builtin_amdgcn_readfirstlane((int)(tid >> 6)); // 0..3
    const int t0  = tg * 16;
    const float* wk = cw + (size_t)sk * (84 * 64);

    float acc[16];
#pragma unroll
    for (int j = 0; j < 16; ++j) acc[j] = 0.f;

#pragma unroll 4
    for (int tau = 0; tau < 84; ++tau) {
        const float wv = wk[tau * 64 + hw];      // coalesced 256 B / wave
#pragma unroll
        for (int j = 0; j < 16; ++j) acc[j] += wv * WD.v[tau][t0 + j]; // s_load
    }

    const int nt  = n >> 4;
    const int fr  = n & 15;
    const int fq  = (hw >> 3) & 3;
    const int jj  = hw & 7;
    const int kbh = hw >> 5;                     // kb = sigma*2 + (hw>>5)
#pragma unroll
    for (int j = 0; j < 16; ++j) {
        const int t = t0 + j;                    // sigma
        const size_t idx =
            ((((size_t)(s * 128 + t * 2 + kbh)) * 8 + nt) * 64 + fq * 16 + fr) * 8 + jj;
        Wf[idx] = f32_bf16(acc[j]);
    }
}

// ---------------------------------------------------------------------------
// Kernel 2: LDS-staged double-buffered MFMA GEMM (m97/T3 pattern).
// Grid 64*KQ blocks (XCD-swizzled) = kq x s x mt; 256 thr (4 waves, 2m x 2n).
// Block tile 128m x 128n, BK=32, NSTEP=128/KQ steps over K-range 4096/KQ.
// A (fp32) staged via global_load_lds with XOR-swizzled SOURCE address
// (LDS dest linear, read side applies the same swizzle); B (bf16 fragment
// order) staged linearly. Counted vmcnt(6), raw s_barrier — loads stay in
// flight across barriers. Partials to P[kq].
// ---------------------------------------------------------------------------
template <int KQ>
__global__ __launch_bounds__(256) void gemm_f(const float* __restrict__ X,
                                              const u16* __restrict__ Wf,
                                              float* __restrict__ P) {
    constexpr int NSTEP = 128 / KQ;              // BK=32 steps per block
    __shared__ float As[2][4096];                // [128 m][32 k] fp32, 16 KB x2
    __shared__ u16   Bs[2][4096];                // 8 fragments x 1 KB,  8 KB x2

    const int tid  = threadIdx.x;
    const int lane = tid & 63;
    const int w    = tid >> 6;
    const int wm   = w >> 1, wn = w & 1;
    const int fr   = lane & 15;
    const int fq   = lane >> 4;

    const int bid  = blockIdx.x;                 // grid = 64*KQ, %8 == 0
    const int wg   = (bid & 7) * (8 * KQ) + (bid >> 3);   // XCD-chunked
    const int mt   = wg & 15;
    const int s    = (wg >> 4) & 3;
    const int kq   = wg >> 6;                    // 0..KQ-1

    // ---- staging addresses -------------------------------------------------
    // A: thread t, issue i (0..3): LDS linear byte L = i*4096 + t*16
    //    -> m = i*32 + (t>>3), row-byte b = (t&7)*16, source byte b ^ swz(m)
    const int am   = tid >> 3;                   // m (i=0); +32 per issue
    const int ab   = ((tid & 7) * 16) ^ ((am & 7) << 4);  // pre-swizzled src byte
    const float* xa = X + (size_t)(mt * 128 + am) * 16384 + s * 4096
                        + (size_t)kq * (4096 / KQ) + (ab >> 2);
    // B: thread t, issue j (0..1): byte j*4096 + t*16 of the step's 8 KB chunk
    const char* wb0 = (const char*)Wf + ((size_t)(s * 128 + kq * NSTEP) << 13)
                        + (size_t)tid * 16;

    f32x4 acc[4][4];
#pragma unroll
    for (int mi = 0; mi < 4; ++mi)
#pragma unroll
        for (int ni = 0; ni < 4; ++ni) acc[mi][ni] = (f32x4){0.f, 0.f, 0.f, 0.f};

#define STAGE(buf, step)                                                       \
    do {                                                                       \
        char* la = (char*)&As[buf][0] + tid * 16;                              \
        char* lb = (char*)&Bs[buf][0] + tid * 16;                              \
        const float* ga = xa + (size_t)(step) * 32;                            \
        const char*  gb = wb0 + ((size_t)(step) << 13);                        \
        gl16(ga,            la);                                               \
        gl16(ga + 524288,   la + 4096);                                        \
        gl16(ga + 1048576,  la + 8192);                                        \
        gl16(ga + 1572864,  la + 12288);                                       \
        gl16(gb,            lb);                                               \
        gl16(gb + 4096,     lb + 4096);                                        \
    } while (0)

    STAGE(0, 0);
    int cur = 0;
#pragma unroll 1
    for (int step = 0; step < NSTEP; ++step) {
        if (step + 1 < NSTEP) {
            STAGE(cur ^ 1, step + 1);
            asm volatile("s_waitcnt vmcnt(6)" ::: "memory");   // cur landed, next in flight
        } else {
            asm volatile("s_waitcnt vmcnt(0)" ::: "memory");
        }
        __builtin_amdgcn_s_barrier();

        const float* Ab = &As[cur][0];
        const u16*   Bb = &Bs[cur][0];
        bf16x8 bfr[4];
#pragma unroll
        for (int ni = 0; ni < 4; ++ni)
            bfr[ni] = *reinterpret_cast<const bf16x8*>(
                Bb + ((wn * 4 + ni) * 64 + lane) * 8);
        const int swz = (fr & 7) << 4;
        const int b0  = (fq * 32) ^ swz;
        const int b1  = (fq * 32 + 16) ^ swz;
#pragma unroll
        for (int mi = 0; mi < 4; ++mi) {
            const int m = wm * 64 + mi * 16 + fr;
            const f32x4 r0 = *reinterpret_cast<const f32x4*>(Ab + m * 32 + (b0 >> 2));
            const f32x4 r1 = *reinterpret_cast<const f32x4*>(Ab + m * 32 + (b1 >> 2));
            union { u32 u[4]; bf16x8 v; } av;
            av.u[0] = pack2_bf16(r0.x, r0.y); av.u[1] = pack2_bf16(r0.z, r0.w);
            av.u[2] = pack2_bf16(r1.x, r1.y); av.u[3] = pack2_bf16(r1.z, r1.w);
#pragma unroll
            for (int ni = 0; ni < 4; ++ni)
                acc[mi][ni] = __builtin_amdgcn_mfma_f32_16x16x32_bf16(
                    av.v, bfr[ni], acc[mi][ni], 0, 0, 0);
        }
        asm volatile("s_waitcnt lgkmcnt(0)" ::: "memory");     // my ds_reads done
        __builtin_amdgcn_s_barrier();                          // before overwrite
        cur ^= 1;
    }
#undef STAGE

    // partial write: P[kq][mt*128 + wm*64 + mi*16 + fq*4 + r][s*128 + wn*64 + ni*16 + fr]
    float* pg = P + (size_t)kq * (2048 * 512)
                  + (size_t)(mt * 128 + wm * 64) * 512 + s * 128 + wn * 64 + fr;
#pragma unroll
    for (int mi = 0; mi < 4; ++mi)
#pragma unroll
        for (int ni = 0; ni < 4; ++ni)
#pragma unroll
            for (int r = 0; r < 4; ++r)
                pg[(size_t)(mi * 16 + fq * 4 + r) * 512 + ni * 16] = acc[mi][ni][r];
}

// ---------------------------------------------------------------------------
// Kernel 3: reduce K-slices, add bias, leaky-ReLU.
// ---------------------------------------------------------------------------
__global__ __launch_bounds__(256) void reduce_k(const float* __restrict__ P,
                                                const float* __restrict__ bias,
                                                float* __restrict__ out, int nks) {
    const int t = blockIdx.x * 256 + threadIdx.x;     // 0..262143
    const size_t base = (size_t)t * 4;
    f32x4 sum = {0.f, 0.f, 0.f, 0.f};
    for (int k = 0; k < nks; ++k)
        sum += *reinterpret_cast<const f32x4*>(P + (size_t)k * (2048 * 512) + base);
    const f32x4 b = *reinterpret_cast<const f32x4*>(bias + (base & 511));
    f32x4 o = sum + b;
    o.x = o.x > 0.f ? o.x : 0.01f * o.x;
    o.y = o.y > 0.f ? o.y : 0.01f * o.y;
    o.z = o.z > 0.f ? o.z : 0.01f * o.z;
    o.w = o.w > 0.f ? o.w : 0.01f * o.w;
    __builtin_nontemporal_store(o, reinterpret_cast<f32x4*>(out + base));
}

// ---------------------------------------------------------------------------
extern "C" void kernel_launch(void* const* d_in, const int* in_sizes, int n_in,
                              void* d_out, int out_size, void* d_ws, size_t ws_size,
                              hipStream_t stream) {
    const float* x  = (const float*)d_in[0];   // [2048,1,256,8,8] fp32
    const float* cw = (const float*)d_in[1];   // [4,128,84,8,8]   fp32
    const float* cb = (const float*)d_in[2];   // [4,128]          fp32
    float* out = (float*)d_out;                // [2048,512]       fp32

    u16*   Wf = (u16*)d_ws;                              // 4 MiB
    float* P  = (float*)((char*)d_ws + (4u << 20));      // KQ * 4 MiB partials

    const size_t MN = (size_t)2048 * 512 * 4;
    fold_w<<<512, 256, 0, stream>>>(cw, Wf);
    if (ws_size >= (4u << 20) + 8 * MN) {
        gemm_f<8><<<512, 256, 0, stream>>>(x, Wf, P);
        reduce_k<<<1024, 256, 0, stream>>>(P, cb, out, 8);
    } else {
        gemm_f<4><<<256, 256, 0, stream>>>(x, Wf, P);
        reduce_k<<<1024, 256, 0, stream>>>(P, cb, out, 4);
    }
}